// Round 12
// baseline (588.570 us; speedup 1.0000x reference)
//
#include <hip/hip_runtime.h>
#include <float.h>

#define F_DIM 256
#define N_DIM 512
#define B_DIM 192
#define K_TOP 10

typedef __attribute__((ext_vector_type(8))) short short8;
typedef __attribute__((ext_vector_type(4))) float f32x4;

__device__ inline unsigned short f2bf(float x) {
    unsigned u = __builtin_bit_cast(unsigned, x);
    return (unsigned short)((u + 0x7fffu + ((u >> 16) & 1u)) >> 16);
}

// ---------------------------------------------------------------------------
// k_combine (grid 514):
//   bx<256 : Wt1[j][f=bx] = bf16( sum_h g_w[h,f]*w1[h,j] )
//   bx==256: bc[j] = sum_h g_b[h]*w1[h,j]
//   bx>256 : W2t[j][f] = bf16(w2[f][j])
// ---------------------------------------------------------------------------
__global__ __launch_bounds__(256) void k_combine(const float* __restrict__ g_w,
                                                 const float* __restrict__ g_b,
                                                 const float* __restrict__ w1,
                                                 const float* __restrict__ w2,
                                                 unsigned short* __restrict__ Wt1,
                                                 float* __restrict__ bc,
                                                 unsigned short* __restrict__ W2t) {
    const int j = threadIdx.x;
    const int bx = blockIdx.x;
    if (bx < F_DIM) {
        float acc = 0.f;
        for (int h = 0; h < F_DIM; ++h) acc += g_w[h * F_DIM + bx] * w1[h * F_DIM + j];
        Wt1[j * F_DIM + bx] = f2bf(acc);
    } else if (bx == F_DIM) {
        float acc = 0.f;
        for (int h = 0; h < F_DIM; ++h) acc += g_b[h] * w1[h * F_DIM + j];
        bc[j] = acc;
    } else {
        int f = bx - F_DIM - 1;
        W2t[j * F_DIM + f] = f2bf(w2[f * F_DIM + j]);
    }
}

// ---------------------------------------------------------------------------
// k_to_bf16t: vt[b][n][f] = bf16(v[b][f][n])
// ---------------------------------------------------------------------------
__global__ __launch_bounds__(256) void k_to_bf16t(const float* __restrict__ v,
                                                  unsigned short* __restrict__ vt) {
    __shared__ float tile[32][33];
    const int b = blockIdx.z;
    const int n0 = blockIdx.x * 32;
    const int f0 = blockIdx.y * 32;
    const int tx = threadIdx.x & 31, ty = threadIdx.x >> 5;
    const float* vb = v + (size_t)b * F_DIM * N_DIM;
#pragma unroll
    for (int q = 0; q < 4; ++q)
        tile[ty + q * 8][tx] = vb[(size_t)(f0 + ty + q * 8) * N_DIM + n0 + tx];
    __syncthreads();
    const int wn = threadIdx.x >> 4;
    const int wf = threadIdx.x & 15;
    unsigned* vt32 = (unsigned*)vt;
#pragma unroll
    for (int q2 = 0; q2 < 2; ++q2) {
        int row = wn + q2 * 16;
        unsigned lo = f2bf(tile[wf * 2][row]);
        unsigned hi = f2bf(tile[wf * 2 + 1][row]);
        vt32[(size_t)(b * N_DIM + n0 + row) * (F_DIM / 2) + (f0 >> 1) + wf] = lo | (hi << 16);
    }
}

// ---------------------------------------------------------------------------
// k_topk_reg v4: m-split waves (R10 geometry) + T14 async-STAGE split:
// chunk c+1 is loaded into registers BEFORE chunk c's MFMA phase (latency
// hides under compute), ds_written after the read-barrier. Same sid->(row,
// slot)->LDS mapping as v3 -> identical stage bytes -> bit-identical results.
// scr padded to stride 6 (48B, 16B-aligned) to kill 4-way merge conflicts.
// ---------------------------------------------------------------------------
__global__ __launch_bounds__(256, 4) void k_topk_reg(const unsigned short* __restrict__ vt,
                                                     float* __restrict__ deg,
                                                     int* __restrict__ idxb,
                                                     float* __restrict__ wb) {
    __shared__ unsigned short stage[N_DIM * 32];   // 32 KB: one 512x32 chunk
    __shared__ uint2 scr[32][6];                   // [row][wave(pad 6)] candidates

    const int lid = blockIdx.x;                    // 3072 blocks
    const int slot = lid >> 3;                     // 0..383
    const int b = (lid & 7) + 8 * (slot >> 4);     // 24 batches per XCD
    const int n0 = (slot & 15) * 32;

    const int t = threadIdx.x;
    const int w = t >> 6;
    const int l = t & 63;
    const int l15 = l & 15;
    const int g = l >> 4;
    const int mbase = w * 128;
    const unsigned short* vtb = vt + (size_t)b * N_DIM * F_DIM;

    f32x4 acc[8][2];
#pragma unroll
    for (int mt = 0; mt < 8; ++mt) {
        acc[mt][0] = (f32x4){0.f, 0.f, 0.f, 0.f};
        acc[mt][1] = (f32x4){0.f, 0.f, 0.f, 0.f};
    }

    uint4 pf[8];
#define LOADR(c)                                                                 \
    {                                                                            \
        _Pragma("unroll")                                                        \
        for (int k = 0; k < 8; ++k) {                                            \
            int sid = k * 256 + t;                                               \
            int row = sid >> 2;                                                  \
            int sl = sid & 3;                                                    \
            pf[k] = *(const uint4*)(vtb + (size_t)row * F_DIM + (c) * 32 +       \
                                    ((sl ^ ((row >> 1) & 3)) << 3));             \
        }                                                                        \
    }

    LOADR(0);
    const int slx = g ^ ((l15 >> 1) & 3);
    for (int c = 0; c < 8; ++c) {
        __syncthreads();                 // all waves done reading prev chunk
#pragma unroll
        for (int k = 0; k < 8; ++k)
            *(uint4*)((char*)&stage[0] + (size_t)(k * 256 + t) * 16) = pf[k];
        if (c < 7) LOADR(c + 1);         // issue next-chunk loads under MFMA
        __syncthreads();                 // stage ready
        const char* sb = (const char*)&stage[0];
        short8 b0 = *(const short8*)(sb + (n0 + l15) * 64 + (slx << 4));
        short8 b1 = *(const short8*)(sb + (n0 + 16 + l15) * 64 + (slx << 4));
#pragma unroll
        for (int mt = 0; mt < 8; ++mt) {
            const int mrow = mbase + mt * 16 + l15;
            short8 a = *(const short8*)(sb + mrow * 64 + (slx << 4));
            acc[mt][0] = __builtin_amdgcn_mfma_f32_16x16x32_bf16(a, b0, acc[mt][0], 0, 0, 0);
            acc[mt][1] = __builtin_amdgcn_mfma_f32_16x16x32_bf16(a, b1, acc[mt][1], 0, 0, 0);
        }
    }
#undef LOADR

    // ---- top-10: rows r0 = n0+l15 (nt=0), r1 = n0+16+l15 (nt=1) ----
    const int grow0 = b * N_DIM + n0 + l15;
    float sum0 = 0.f, sum1 = 0.f;
    for (int it = 0; it < K_TOP; ++it) {
        float cv[2]; int cm[2];
#pragma unroll
        for (int nt = 0; nt < 2; ++nt) {
            float tv[16]; int te[16];
#pragma unroll
            for (int p = 0; p < 16; ++p) {
                const int e0 = 2 * p, e1 = 2 * p + 1;
                float a = acc[e0 >> 2][nt][e0 & 3];
                float bb2 = acc[e1 >> 2][nt][e1 & 3];
                bool tk = bb2 > a;                 // keep lower e on tie
                tv[p] = tk ? bb2 : a;
                te[p] = tk ? e1 : e0;
            }
#pragma unroll
            for (int len = 8; len >= 1; len >>= 1) {
#pragma unroll
                for (int i2 = 0; i2 < 8; ++i2) {
                    if (i2 < len) {
                        bool tk = tv[i2 + len] > tv[i2];
                        tv[i2] = tk ? tv[i2 + len] : tv[i2];
                        te[i2] = tk ? te[i2 + len] : te[i2];
                    }
                }
            }
            cv[nt] = tv[0];
            cm[nt] = mbase + ((te[0] >> 2) << 4) + (g << 2) + (te[0] & 3);
        }
        // cross-g reduce within wave (global-m tie-break)
#pragma unroll
        for (int off = 16; off <= 32; off <<= 1) {
#pragma unroll
            for (int nt = 0; nt < 2; ++nt) {
                float ov = __shfl_xor(cv[nt], off, 64);
                int om = __shfl_xor(cm[nt], off, 64);
                if (ov > cv[nt] || (ov == cv[nt] && om < cm[nt])) { cv[nt] = ov; cm[nt] = om; }
            }
        }
        // wave candidates -> scratch
        if (l < 16) {
            scr[l15][w] = make_uint2(__builtin_bit_cast(unsigned, cv[0]), (unsigned)cm[0]);
            scr[16 + l15][w] = make_uint2(__builtin_bit_cast(unsigned, cv[1]), (unsigned)cm[1]);
        }
        __syncthreads();
        // redundant 4-way merge per row (waves in ascending-m order)
        float wv[2]; int wm[2];
#pragma unroll
        for (int nt = 0; nt < 2; ++nt) {
            const uint2* sr = &scr[nt * 16 + l15][0];
            uint4 q01 = *(const uint4*)&sr[0];
            uint4 q23 = *(const uint4*)&sr[2];
            float v0 = __builtin_bit_cast(float, q01.x); int m0 = (int)q01.y;
            float v1 = __builtin_bit_cast(float, q01.z); int m1 = (int)q01.w;
            float v2 = __builtin_bit_cast(float, q23.x); int m2 = (int)q23.y;
            float v3 = __builtin_bit_cast(float, q23.z); int m3 = (int)q23.w;
            bool t1 = (v1 > v0) || (v1 == v0 && m1 < m0);
            float va = t1 ? v1 : v0; int ma = t1 ? m1 : m0;
            bool t2 = (v3 > v2) || (v3 == v2 && m3 < m2);
            float vb2 = t2 ? v3 : v2; int mb = t2 ? m3 : m2;
            bool t3 = (vb2 > va) || (vb2 == va && mb < ma);
            wv[nt] = t3 ? vb2 : va; wm[nt] = t3 ? mb : ma;
        }
        __syncthreads();   // scratch reusable next iteration
        sum0 += wv[0]; sum1 += wv[1];
        if (w == 0 && l < 16) {
            idxb[grow0 * K_TOP + it] = wm[0];
            wb[grow0 * (K_TOP + 1) + it] = wv[0];
            idxb[(grow0 + 16) * K_TOP + it] = wm[1];
            wb[(grow0 + 16) * (K_TOP + 1) + it] = wv[1];
        }
        if (it < K_TOP - 1) {
#pragma unroll
            for (int nt = 0; nt < 2; ++nt) {
                const int mwin = wm[nt];
                const bool own = ((mwin >> 7) == w) && (((mwin >> 2) & 3) == g);
                const int eo = (((mwin >> 4) & 7) << 2) | (mwin & 3);
#pragma unroll
                for (int ee = 0; ee < 32; ++ee)
                    acc[ee >> 2][nt][ee & 3] =
                        (own && ee == eo) ? -FLT_MAX : acc[ee >> 2][nt][ee & 3];
            }
        }
    }
    if (w == 0 && l < 16) {
        deg[grow0] = sum0 + 1.0f;
        deg[grow0 + 16] = sum1 + 1.0f;
    }
}

// ---------------------------------------------------------------------------
// k_scale: wbs[row][i] = dn * wb[row][i] * dm (i<10); wbs[row][10] = dn*dn.
// ---------------------------------------------------------------------------
__global__ __launch_bounds__(256) void k_scale(const float* __restrict__ deg,
                                               const int* __restrict__ idxb,
                                               const float* __restrict__ wb,
                                               float* __restrict__ wbs) {
    const int row = blockIdx.x * 256 + threadIdx.x;
    const float dg = deg[row];
    const float dn = (dg == 0.f) ? 0.f : 1.f / sqrtf(dg);
    const int bb = (row >> 9) << 9;
#pragma unroll
    for (int i = 0; i < K_TOP; ++i) {
        int m = idxb[row * K_TOP + i];
        float dgm = deg[bb + m];
        float dm = (dgm == 0.f) ? 0.f : 1.f / sqrtf(dgm);
        wbs[row * 12 + i] = dn * wb[row * (K_TOP + 1) + i] * dm;
    }
    wbs[row * 12 + K_TOP] = dn * dn;
}

// ---------------------------------------------------------------------------
// k_gemm_mfma: 64x256 blocks, 4 waves (quadrants), 4 waves/SIMD (R11 v2).
// ---------------------------------------------------------------------------
template <bool ADD_BIAS>
__global__ __launch_bounds__(256, 4) void k_gemm_mfma(const unsigned short* __restrict__ At,
                                                      const unsigned short* __restrict__ Wt,
                                                      const float* __restrict__ bias,
                                                      float* __restrict__ C) {
    const int b = blockIdx.y;
    const int w = threadIdx.x >> 6;
    const int l = threadIdx.x & 63;
    const int l15 = l & 15;
    const int g = l >> 4;
    const int n0w = blockIdx.x * 64 + (w >> 1) * 32;   // 32-row group
    const int j0w = (w & 1) * 128;                     // 128-col group
    const unsigned short* Ab = At + (size_t)b * N_DIM * F_DIM;

    f32x4 acc0[8], acc1[8];
#pragma unroll
    for (int jt = 0; jt < 8; ++jt) {
        acc0[jt] = (f32x4){0.f, 0.f, 0.f, 0.f};
        acc1[jt] = (f32x4){0.f, 0.f, 0.f, 0.f};
    }

    for (int s = 0; s < 8; ++s) {
        short8 a0 = *(const short8*)(Ab + (size_t)(n0w + l15) * F_DIM + s * 32 + g * 8);
        short8 a1 = *(const short8*)(Ab + (size_t)(n0w + 16 + l15) * F_DIM + s * 32 + g * 8);
#pragma unroll
        for (int jt = 0; jt < 8; ++jt) {
            short8 bf = *(const short8*)(Wt + (size_t)(j0w + jt * 16 + l15) * F_DIM + s * 32 + g * 8);
            acc0[jt] = __builtin_amdgcn_mfma_f32_16x16x32_bf16(a0, bf, acc0[jt], 0, 0, 0);
            acc1[jt] = __builtin_amdgcn_mfma_f32_16x16x32_bf16(a1, bf, acc1[jt], 0, 0, 0);
        }
    }

#pragma unroll
    for (int jt = 0; jt < 8; ++jt) {
        const int col = j0w + jt * 16 + l15;
        float bv = ADD_BIAS ? bias[col] : 0.f;
#pragma unroll
        for (int q = 0; q < 4; ++q) {
            int r0 = n0w + g * 4 + q;
            C[((size_t)b * N_DIM + r0) * F_DIM + col] = acc0[jt][q] + bv;
            int r1 = n0w + 16 + g * 4 + q;
            C[((size_t)b * N_DIM + r1) * F_DIM + col] = acc1[jt][q] + bv;
        }
    }
}

// ---------------------------------------------------------------------------
// k_spmm_bf16: x1 = relu(A_hat @ h1 + b1) with PRE-SCALED weights. bf16 out.
// ---------------------------------------------------------------------------
__global__ __launch_bounds__(256) void k_spmm_bf16(const float* __restrict__ X,
                                                   const int* __restrict__ idxb,
                                                   const float* __restrict__ wbs,
                                                   const float* __restrict__ bias,
                                                   unsigned short* __restrict__ Y) {
    const int lid = blockIdx.x;                 // 24576 blocks
    const int slot = lid >> 3;                  // 0..3071
    const int b = (lid & 7) + 8 * (slot >> 7);  // 2 batches/XCD concurrent
    const int rowblk = slot & 127;
    const int w = threadIdx.x >> 6;
    const int l = threadIdx.x & 63;
    const int row = b * N_DIM + rowblk * 4 + w;

    const float* Xb = X + ((size_t)b << 9) * F_DIM;
    const int* id = idxb + row * K_TOP;
    const float* ww = wbs + (size_t)row * 12;

    float4 bv = ((const float4*)bias)[l];
    float4 xv = ((const float4*)(X + (size_t)row * F_DIM))[l];
    const float ws = ww[K_TOP];
    float4 acc;
    acc.x = ws * xv.x + bv.x; acc.y = ws * xv.y + bv.y;
    acc.z = ws * xv.z + bv.z; acc.w = ws * xv.w + bv.w;
#pragma unroll
    for (int i = 0; i < K_TOP; ++i) {
        float wi = ww[i];
        float4 gv = ((const float4*)(Xb + ((size_t)id[i] << 8)))[l];
        acc.x += wi * gv.x; acc.y += wi * gv.y;
        acc.z += wi * gv.z; acc.w += wi * gv.w;
    }
    acc.x = fmaxf(acc.x, 0.f); acc.y = fmaxf(acc.y, 0.f);
    acc.z = fmaxf(acc.z, 0.f); acc.w = fmaxf(acc.w, 0.f);
    uint2 p;
    p.x = (unsigned)f2bf(acc.x) | ((unsigned)f2bf(acc.y) << 16);
    p.y = (unsigned)f2bf(acc.z) | ((unsigned)f2bf(acc.w) << 16);
    ((uint2*)Y)[(size_t)row * (F_DIM / 4) + l] = p;
}

// ---------------------------------------------------------------------------
// k_spmm_trans: x2 = A_hat @ h2 + b2 (pre-scaled weights), out = x2^T + v.
// 16n x 128f tiles: 4 batches/XCD concurrent = 1 MB << L2.
// ---------------------------------------------------------------------------
__global__ __launch_bounds__(256) void k_spmm_trans(const float* __restrict__ X,
                                                    const int* __restrict__ idxb,
                                                    const float* __restrict__ wbs,
                                                    const float* __restrict__ bias,
                                                    const float* __restrict__ v,
                                                    float* __restrict__ out) {
    __shared__ float tile[16][132];
    const int lid = blockIdx.x;                 // 12288 blocks
    const int slot = lid >> 3;                  // 0..1535
    const int b = (lid & 7) + 8 * (slot >> 6);  // 64 tiles/batch
    const int tl = slot & 63;
    const int n0 = (tl & 31) * 16;
    const int f0 = (tl >> 5) * 128;
    const int w = threadIdx.x >> 6;
    const int l = threadIdx.x & 63;

    const float* Xb = X + ((size_t)b << 9) * F_DIM;
    const int rl = l >> 5;                      // row sub-index (0/1)
    const int fq = l & 31;                      // f-quad within half-panel
    float4 bv = ((const float4*)bias)[(f0 >> 2) + fq];

#pragma unroll
    for (int p2 = 0; p2 < 2; ++p2) {
        const int rloc = p2 * 8 + w * 2 + rl;
        const int row = b * N_DIM + n0 + rloc;
        const int* id = idxb + row * K_TOP;
        const float* ww = wbs + (size_t)row * 12;
        float4 xv = ((const float4*)(X + (size_t)row * F_DIM + f0))[fq];
        const float ws = ww[K_TOP];
        float4 acc;
        acc.x = ws * xv.x + bv.x; acc.y = ws * xv.y + bv.y;
        acc.z = ws * xv.z + bv.z; acc.w = ws * xv.w + bv.w;
#pragma unroll
        for (int i = 0; i < K_TOP; ++i) {
            float wi = ww[i];
            float4 gv = ((const float4*)(Xb + ((size_t)id[i] << 8) + f0))[fq];
            acc.x += wi * gv.x; acc.y += wi * gv.y;
            acc.z += wi * gv.z; acc.w += wi * gv.w;
        }
        tile[rloc][fq * 4 + 0] = acc.x;
        tile[rloc][fq * 4 + 1] = acc.y;
        tile[rloc][fq * 4 + 2] = acc.z;
        tile[rloc][fq * 4 + 3] = acc.w;
    }
    __syncthreads();

    const int i4 = l & 3, fj = l >> 2;
#pragma unroll
    for (int k = 0; k < 2; ++k) {
        const int fl = k * 64 + w * 16 + fj;
        const size_t vo = (size_t)b * F_DIM * N_DIM + (size_t)(f0 + fl) * N_DIM + n0;
        float4 vv = ((const float4*)(v + vo))[i4];
        float4 o;
        o.x = tile[i4 * 4 + 0][fl] + vv.x;
        o.y = tile[i4 * 4 + 1][fl] + vv.y;
        o.z = tile[i4 * 4 + 2][fl] + vv.z;
        o.w = tile[i4 * 4 + 3][fl] + vv.w;
        ((float4*)(out + vo))[i4] = o;
    }
}

// ---------------------------------------------------------------------------
extern "C" void kernel_launch(void* const* d_in, const int* in_sizes, int n_in,
                              void* d_out, int out_size, void* d_ws, size_t ws_size,
                              hipStream_t stream) {
    const float* v   = (const float*)d_in[0];
    const float* g_w = (const float*)d_in[1];
    const float* g_b = (const float*)d_in[2];
    const float* w1  = (const float*)d_in[3];
    const float* b1  = (const float*)d_in[4];
    const float* w2  = (const float*)d_in[5];
    const float* b2  = (const float*)d_in[6];
    float* out = (float*)d_out;

    const size_t S = (size_t)B_DIM * N_DIM * F_DIM;
    float* bufA = (float*)d_ws;                     // h1, then h2 (fp32)
    float* bufB = bufA + S;                         // vt/x1bf in lower half
    float* bc   = bufB + S;
    float* deg  = bc + F_DIM;
    float* wb   = deg + (size_t)B_DIM * N_DIM;      // raw top-10 values
    int*   idxb = (int*)(wb + (size_t)B_DIM * N_DIM * (K_TOP + 1));
    unsigned short* Wt1 = (unsigned short*)(idxb + (size_t)B_DIM * N_DIM * K_TOP);
    unsigned short* W2t = Wt1 + F_DIM * F_DIM;

    unsigned short* vt   = (unsigned short*)bufB;   // lower half of bufB
    unsigned short* x1bf = (unsigned short*)bufB;
    float* wbs = bufB + S / 2;                      // upper half of bufB (free)

    k_combine<<<dim3(2 * F_DIM + 2), 256, 0, stream>>>(g_w, g_b, w1, w2, Wt1, bc, W2t);
    k_to_bf16t<<<dim3(N_DIM / 32, F_DIM / 32, B_DIM), 256, 0, stream>>>(v, vt);
    // affinity + top-10 (m-split waves, reg-prefetch staging, LDS merge)
    k_topk_reg<<<dim3(B_DIM * (N_DIM / 32)), 256, 0, stream>>>(vt, deg, idxb, wb);
    // pre-scale edge weights once
    k_scale<<<dim3(B_DIM * N_DIM / 256), 256, 0, stream>>>(deg, idxb, wb, wbs);
    // h1 = vt @ Wt1^T + bc -> bufA  (64x256 blocks, 4 waves/SIMD)
    k_gemm_mfma<true><<<dim3(N_DIM / 64, B_DIM), 256, 0, stream>>>(vt, Wt1, bc, bufA);
    // x1 = relu(A_hat @ h1 + b1) -> x1bf (bf16)
    k_spmm_bf16<<<dim3(B_DIM * N_DIM / 4), 256, 0, stream>>>(bufA, idxb, wbs, b1, x1bf);
    // h2 = x1bf @ W2t^T -> bufA
    k_gemm_mfma<false><<<dim3(N_DIM / 64, B_DIM), 256, 0, stream>>>(x1bf, W2t, nullptr, bufA);
    // out = (A_hat @ h2 + b2)^T + v
    k_spmm_trans<<<dim3(B_DIM * N_DIM / 16 * 2), 256, 0, stream>>>(bufA, idxb, wbs, b2, v, out);
}

// Round 13
// 459.372 us; speedup vs baseline: 1.2812x; 1.2812x over previous
//
#include <hip/hip_runtime.h>
#include <float.h>

#define F_DIM 256
#define N_DIM 512
#define B_DIM 192
#define K_TOP 10

typedef __attribute__((ext_vector_type(8))) short short8;
typedef __attribute__((ext_vector_type(4))) float f32x4;

__device__ inline unsigned short f2bf(float x) {
    unsigned u = __builtin_bit_cast(unsigned, x);
    return (unsigned short)((u + 0x7fffu + ((u >> 16) & 1u)) >> 16);
}

// ---------------------------------------------------------------------------
// k_combine (grid 514):
//   bx<256 : Wt1[j][f=bx] = bf16( sum_h g_w[h,f]*w1[h,j] )
//   bx==256: bc[j] = sum_h g_b[h]*w1[h,j]
//   bx>256 : W2t[j][f] = bf16(w2[f][j])
// ---------------------------------------------------------------------------
__global__ __launch_bounds__(256) void k_combine(const float* __restrict__ g_w,
                                                 const float* __restrict__ g_b,
                                                 const float* __restrict__ w1,
                                                 const float* __restrict__ w2,
                                                 unsigned short* __restrict__ Wt1,
                                                 float* __restrict__ bc,
                                                 unsigned short* __restrict__ W2t) {
    const int j = threadIdx.x;
    const int bx = blockIdx.x;
    if (bx < F_DIM) {
        float acc = 0.f;
        for (int h = 0; h < F_DIM; ++h) acc += g_w[h * F_DIM + bx] * w1[h * F_DIM + j];
        Wt1[j * F_DIM + bx] = f2bf(acc);
    } else if (bx == F_DIM) {
        float acc = 0.f;
        for (int h = 0; h < F_DIM; ++h) acc += g_b[h] * w1[h * F_DIM + j];
        bc[j] = acc;
    } else {
        int f = bx - F_DIM - 1;
        W2t[j * F_DIM + f] = f2bf(w2[f * F_DIM + j]);
    }
}

// ---------------------------------------------------------------------------
// k_to_bf16t: vt[b][n][f] = bf16(v[b][f][n])
// ---------------------------------------------------------------------------
__global__ __launch_bounds__(256) void k_to_bf16t(const float* __restrict__ v,
                                                  unsigned short* __restrict__ vt) {
    __shared__ float tile[32][33];
    const int b = blockIdx.z;
    const int n0 = blockIdx.x * 32;
    const int f0 = blockIdx.y * 32;
    const int tx = threadIdx.x & 31, ty = threadIdx.x >> 5;
    const float* vb = v + (size_t)b * F_DIM * N_DIM;
#pragma unroll
    for (int q = 0; q < 4; ++q)
        tile[ty + q * 8][tx] = vb[(size_t)(f0 + ty + q * 8) * N_DIM + n0 + tx];
    __syncthreads();
    const int wn = threadIdx.x >> 4;
    const int wf = threadIdx.x & 15;
    unsigned* vt32 = (unsigned*)vt;
#pragma unroll
    for (int q2 = 0; q2 < 2; ++q2) {
        int row = wn + q2 * 16;
        unsigned lo = f2bf(tile[wf * 2][row]);
        unsigned hi = f2bf(tile[wf * 2 + 1][row]);
        vt32[(size_t)(b * N_DIM + n0 + row) * (F_DIM / 2) + (f0 >> 1) + wf] = lo | (hi << 16);
    }
}

// ---------------------------------------------------------------------------
// k_topk_reg v5: staging reverted to R11's measured global_load_lds form
// (R12's reg-prefetch spilled: 128 AGPR+VGPR budget at 4 waves/SIMD).
// Selection: cached per-lane chunk-bests (4 chunks of 8 elements). Per iter:
// 9-op combine instead of 93-op rescan; after knockout only the owner's chunk
// is rebuilt under __any() wave-uniform branch. Lexicographic (value, low-e)
// max is a unique selection over a set -> bit-identical to the full rescan.
// ---------------------------------------------------------------------------
__global__ __launch_bounds__(256, 4) void k_topk_reg(const unsigned short* __restrict__ vt,
                                                     float* __restrict__ deg,
                                                     int* __restrict__ idxb,
                                                     float* __restrict__ wb) {
    __shared__ unsigned short stage[N_DIM * 32];   // 32 KB: one 512x32 chunk
    __shared__ uint2 scr[32][6];                   // [row][wave(pad 6)] candidates

    const int lid = blockIdx.x;                    // 3072 blocks
    const int slot = lid >> 3;                     // 0..383
    const int b = (lid & 7) + 8 * (slot >> 4);     // 24 batches per XCD
    const int n0 = (slot & 15) * 32;

    const int t = threadIdx.x;
    const int w = t >> 6;
    const int l = t & 63;
    const int l15 = l & 15;
    const int g = l >> 4;
    const int mbase = w * 128;
    const unsigned short* vtb = vt + (size_t)b * N_DIM * F_DIM;

    f32x4 acc[8][2];
#pragma unroll
    for (int mt = 0; mt < 8; ++mt) {
        acc[mt][0] = (f32x4){0.f, 0.f, 0.f, 0.f};
        acc[mt][1] = (f32x4){0.f, 0.f, 0.f, 0.f};
    }

#define STAGE(c)                                                                 \
    {                                                                            \
        _Pragma("unroll")                                                        \
        for (int k = 0; k < 8; ++k) {                                            \
            int sid = w * 512 + k * 64 + l;                                      \
            int row = sid >> 2;                                                  \
            int sl = sid & 3;                                                    \
            const unsigned short* src = vtb + (size_t)row * F_DIM + (c) * 32 +   \
                                        ((sl ^ ((row >> 1) & 3)) << 3);          \
            __builtin_amdgcn_global_load_lds(                                    \
                (const __attribute__((address_space(1))) void*)src,              \
                (__attribute__((address_space(3))) void*)(                       \
                    (char*)&stage[0] + (size_t)sid * 16),                        \
                16, 0, 0);                                                       \
        }                                                                        \
    }

    const int slx = g ^ ((l15 >> 1) & 3);
    for (int c = 0; c < 8; ++c) {
        STAGE(c);
        asm volatile("s_waitcnt vmcnt(0)" ::: "memory");
        __syncthreads();
        const char* sb = (const char*)&stage[0];
        short8 b0 = *(const short8*)(sb + (n0 + l15) * 64 + (slx << 4));
        short8 b1 = *(const short8*)(sb + (n0 + 16 + l15) * 64 + (slx << 4));
#pragma unroll
        for (int mt = 0; mt < 8; ++mt) {
            const int mrow = mbase + mt * 16 + l15;
            short8 a = *(const short8*)(sb + mrow * 64 + (slx << 4));
            acc[mt][0] = __builtin_amdgcn_mfma_f32_16x16x32_bf16(a, b0, acc[mt][0], 0, 0, 0);
            acc[mt][1] = __builtin_amdgcn_mfma_f32_16x16x32_bf16(a, b1, acc[mt][1], 0, 0, 0);
        }
        __syncthreads();   // before next STAGE overwrites the buffer
    }
#undef STAGE

// best-of-8 for chunk c (elements e = c*8 .. c*8+7), lexicographic (v, -e)
#define BUILD_CHUNK(nt, c, outv, oute)                                           \
    {                                                                            \
        float p0v, p1v, p2v, p3v; int p0e, p1e, p2e, p3e;                        \
        { float a = acc[2*(c)][nt][0], bb = acc[2*(c)][nt][1];                   \
          bool tk = bb > a; p0v = tk ? bb : a; p0e = (c)*8 + (tk ? 1 : 0); }     \
        { float a = acc[2*(c)][nt][2], bb = acc[2*(c)][nt][3];                   \
          bool tk = bb > a; p1v = tk ? bb : a; p1e = (c)*8 + (tk ? 3 : 2); }     \
        { float a = acc[2*(c)+1][nt][0], bb = acc[2*(c)+1][nt][1];               \
          bool tk = bb > a; p2v = tk ? bb : a; p2e = (c)*8 + (tk ? 5 : 4); }     \
        { float a = acc[2*(c)+1][nt][2], bb = acc[2*(c)+1][nt][3];               \
          bool tk = bb > a; p3v = tk ? bb : a; p3e = (c)*8 + (tk ? 7 : 6); }     \
        bool q0 = p1v > p0v; float q0v = q0 ? p1v : p0v; int q0e = q0 ? p1e : p0e; \
        bool q1 = p3v > p2v; float q1v = q1 ? p3v : p2v; int q1e = q1 ? p3e : p2e; \
        bool q2 = q1v > q0v; (outv) = q2 ? q1v : q0v; (oute) = q2 ? q1e : q0e;   \
    }

    float cbv[2][4]; int cbe[2][4];
#pragma unroll
    for (int nt = 0; nt < 2; ++nt) {
        BUILD_CHUNK(nt, 0, cbv[nt][0], cbe[nt][0]);
        BUILD_CHUNK(nt, 1, cbv[nt][1], cbe[nt][1]);
        BUILD_CHUNK(nt, 2, cbv[nt][2], cbe[nt][2]);
        BUILD_CHUNK(nt, 3, cbv[nt][3], cbe[nt][3]);
    }

    // ---- top-10: rows r0 = n0+l15 (nt=0), r1 = n0+16+l15 (nt=1) ----
    const int grow0 = b * N_DIM + n0 + l15;
    float sum0 = 0.f, sum1 = 0.f;
    for (int it = 0; it < K_TOP; ++it) {
        float cv[2]; int cm[2];
#pragma unroll
        for (int nt = 0; nt < 2; ++nt) {
            bool k1 = cbv[nt][1] > cbv[nt][0];
            float va = k1 ? cbv[nt][1] : cbv[nt][0];
            int ea = k1 ? cbe[nt][1] : cbe[nt][0];
            bool k2 = cbv[nt][3] > cbv[nt][2];
            float vb2 = k2 ? cbv[nt][3] : cbv[nt][2];
            int eb = k2 ? cbe[nt][3] : cbe[nt][2];
            bool k3 = vb2 > va;
            cv[nt] = k3 ? vb2 : va;
            int ce = k3 ? eb : ea;
            cm[nt] = mbase + ((ce >> 2) << 4) + (g << 2) + (ce & 3);
        }
        // cross-g reduce within wave (global-m tie-break)
#pragma unroll
        for (int off = 16; off <= 32; off <<= 1) {
#pragma unroll
            for (int nt = 0; nt < 2; ++nt) {
                float ov = __shfl_xor(cv[nt], off, 64);
                int om = __shfl_xor(cm[nt], off, 64);
                if (ov > cv[nt] || (ov == cv[nt] && om < cm[nt])) { cv[nt] = ov; cm[nt] = om; }
            }
        }
        // wave candidates -> scratch
        if (l < 16) {
            scr[l15][w] = make_uint2(__builtin_bit_cast(unsigned, cv[0]), (unsigned)cm[0]);
            scr[16 + l15][w] = make_uint2(__builtin_bit_cast(unsigned, cv[1]), (unsigned)cm[1]);
        }
        __syncthreads();
        // redundant 4-way merge per row (waves in ascending-m order)
        float wv[2]; int wm[2];
#pragma unroll
        for (int nt = 0; nt < 2; ++nt) {
            const uint2* sr = &scr[nt * 16 + l15][0];
            uint4 q01 = *(const uint4*)&sr[0];
            uint4 q23 = *(const uint4*)&sr[2];
            float v0 = __builtin_bit_cast(float, q01.x); int m0 = (int)q01.y;
            float v1 = __builtin_bit_cast(float, q01.z); int m1 = (int)q01.w;
            float v2 = __builtin_bit_cast(float, q23.x); int m2 = (int)q23.y;
            float v3 = __builtin_bit_cast(float, q23.z); int m3 = (int)q23.w;
            bool t1 = (v1 > v0) || (v1 == v0 && m1 < m0);
            float va = t1 ? v1 : v0; int ma = t1 ? m1 : m0;
            bool t2 = (v3 > v2) || (v3 == v2 && m3 < m2);
            float vb2 = t2 ? v3 : v2; int mb = t2 ? m3 : m2;
            bool t3 = (vb2 > va) || (vb2 == va && mb < ma);
            wv[nt] = t3 ? vb2 : va; wm[nt] = t3 ? mb : ma;
        }
        __syncthreads();   // scratch reusable next iteration
        sum0 += wv[0]; sum1 += wv[1];
        if (w == 0 && l < 16) {
            idxb[grow0 * K_TOP + it] = wm[0];
            wb[grow0 * (K_TOP + 1) + it] = wv[0];
            idxb[(grow0 + 16) * K_TOP + it] = wm[1];
            wb[(grow0 + 16) * (K_TOP + 1) + it] = wv[1];
        }
        if (it < K_TOP - 1) {
#pragma unroll
            for (int nt = 0; nt < 2; ++nt) {
                const int mwin = wm[nt];
                const bool own = ((mwin >> 7) == w) && (((mwin >> 2) & 3) == g);
                const int eo = (((mwin >> 4) & 7) << 2) | (mwin & 3);
#pragma unroll
                for (int c = 0; c < 4; ++c) {
                    bool need = own && ((eo >> 3) == c);
                    if (__any(need)) {            // wave-uniform skip branch
#pragma unroll
                        for (int j = 0; j < 8; ++j) {
                            int ee = c * 8 + j;
                            acc[ee >> 2][nt][ee & 3] =
                                (need && ee == eo) ? -FLT_MAX : acc[ee >> 2][nt][ee & 3];
                        }
                        float nv; int ne;
                        BUILD_CHUNK(nt, c, nv, ne);
                        cbv[nt][c] = need ? nv : cbv[nt][c];
                        cbe[nt][c] = need ? ne : cbe[nt][c];
                    }
                }
            }
        }
    }
#undef BUILD_CHUNK
    if (w == 0 && l < 16) {
        deg[grow0] = sum0 + 1.0f;
        deg[grow0 + 16] = sum1 + 1.0f;
    }
}

// ---------------------------------------------------------------------------
// k_scale: wbs[row][i] = dn * wb[row][i] * dm (i<10); wbs[row][10] = dn*dn.
// ---------------------------------------------------------------------------
__global__ __launch_bounds__(256) void k_scale(const float* __restrict__ deg,
                                               const int* __restrict__ idxb,
                                               const float* __restrict__ wb,
                                               float* __restrict__ wbs) {
    const int row = blockIdx.x * 256 + threadIdx.x;
    const float dg = deg[row];
    const float dn = (dg == 0.f) ? 0.f : 1.f / sqrtf(dg);
    const int bb = (row >> 9) << 9;
#pragma unroll
    for (int i = 0; i < K_TOP; ++i) {
        int m = idxb[row * K_TOP + i];
        float dgm = deg[bb + m];
        float dm = (dgm == 0.f) ? 0.f : 1.f / sqrtf(dgm);
        wbs[row * 12 + i] = dn * wb[row * (K_TOP + 1) + i] * dm;
    }
    wbs[row * 12 + K_TOP] = dn * dn;
}

// ---------------------------------------------------------------------------
// k_gemm_mfma: 64x256 blocks, 4 waves (quadrants), 4 waves/SIMD.
// ---------------------------------------------------------------------------
template <bool ADD_BIAS>
__global__ __launch_bounds__(256, 4) void k_gemm_mfma(const unsigned short* __restrict__ At,
                                                      const unsigned short* __restrict__ Wt,
                                                      const float* __restrict__ bias,
                                                      float* __restrict__ C) {
    const int b = blockIdx.y;
    const int w = threadIdx.x >> 6;
    const int l = threadIdx.x & 63;
    const int l15 = l & 15;
    const int g = l >> 4;
    const int n0w = blockIdx.x * 64 + (w >> 1) * 32;   // 32-row group
    const int j0w = (w & 1) * 128;                     // 128-col group
    const unsigned short* Ab = At + (size_t)b * N_DIM * F_DIM;

    f32x4 acc0[8], acc1[8];
#pragma unroll
    for (int jt = 0; jt < 8; ++jt) {
        acc0[jt] = (f32x4){0.f, 0.f, 0.f, 0.f};
        acc1[jt] = (f32x4){0.f, 0.f, 0.f, 0.f};
    }

    for (int s = 0; s < 8; ++s) {
        short8 a0 = *(const short8*)(Ab + (size_t)(n0w + l15) * F_DIM + s * 32 + g * 8);
        short8 a1 = *(const short8*)(Ab + (size_t)(n0w + 16 + l15) * F_DIM + s * 32 + g * 8);
#pragma unroll
        for (int jt = 0; jt < 8; ++jt) {
            short8 bf = *(const short8*)(Wt + (size_t)(j0w + jt * 16 + l15) * F_DIM + s * 32 + g * 8);
            acc0[jt] = __builtin_amdgcn_mfma_f32_16x16x32_bf16(a0, bf, acc0[jt], 0, 0, 0);
            acc1[jt] = __builtin_amdgcn_mfma_f32_16x16x32_bf16(a1, bf, acc1[jt], 0, 0, 0);
        }
    }

#pragma unroll
    for (int jt = 0; jt < 8; ++jt) {
        const int col = j0w + jt * 16 + l15;
        float bv = ADD_BIAS ? bias[col] : 0.f;
#pragma unroll
        for (int q = 0; q < 4; ++q) {
            int r0 = n0w + g * 4 + q;
            C[((size_t)b * N_DIM + r0) * F_DIM + col] = acc0[jt][q] + bv;
            int r1 = n0w + 16 + g * 4 + q;
            C[((size_t)b * N_DIM + r1) * F_DIM + col] = acc1[jt][q] + bv;
        }
    }
}

// ---------------------------------------------------------------------------
// k_spmm_bf16: x1 = relu(A_hat @ h1 + b1) with PRE-SCALED weights. bf16 out.
// ---------------------------------------------------------------------------
__global__ __launch_bounds__(256) void k_spmm_bf16(const float* __restrict__ X,
                                                   const int* __restrict__ idxb,
                                                   const float* __restrict__ wbs,
                                                   const float* __restrict__ bias,
                                                   unsigned short* __restrict__ Y) {
    const int lid = blockIdx.x;                 // 24576 blocks
    const int slot = lid >> 3;                  // 0..3071
    const int b = (lid & 7) + 8 * (slot >> 7);  // 2 batches/XCD concurrent
    const int rowblk = slot & 127;
    const int w = threadIdx.x >> 6;
    const int l = threadIdx.x & 63;
    const int row = b * N_DIM + rowblk * 4 + w;

    const float* Xb = X + ((size_t)b << 9) * F_DIM;
    const int* id = idxb + row * K_TOP;
    const float* ww = wbs + (size_t)row * 12;

    float4 bv = ((const float4*)bias)[l];
    float4 xv = ((const float4*)(X + (size_t)row * F_DIM))[l];
    const float ws = ww[K_TOP];
    float4 acc;
    acc.x = ws * xv.x + bv.x; acc.y = ws * xv.y + bv.y;
    acc.z = ws * xv.z + bv.z; acc.w = ws * xv.w + bv.w;
#pragma unroll
    for (int i = 0; i < K_TOP; ++i) {
        float wi = ww[i];
        float4 gv = ((const float4*)(Xb + ((size_t)id[i] << 8)))[l];
        acc.x += wi * gv.x; acc.y += wi * gv.y;
        acc.z += wi * gv.z; acc.w += wi * gv.w;
    }
    acc.x = fmaxf(acc.x, 0.f); acc.y = fmaxf(acc.y, 0.f);
    acc.z = fmaxf(acc.z, 0.f); acc.w = fmaxf(acc.w, 0.f);
    uint2 p;
    p.x = (unsigned)f2bf(acc.x) | ((unsigned)f2bf(acc.y) << 16);
    p.y = (unsigned)f2bf(acc.z) | ((unsigned)f2bf(acc.w) << 16);
    ((uint2*)Y)[(size_t)row * (F_DIM / 4) + l] = p;
}

// ---------------------------------------------------------------------------
// k_spmm_trans: x2 = A_hat @ h2 + b2 (pre-scaled weights), out = x2^T + v.
// 16n x 128f tiles: 4 batches/XCD concurrent = 1 MB << L2.
// ---------------------------------------------------------------------------
__global__ __launch_bounds__(256) void k_spmm_trans(const float* __restrict__ X,
                                                    const int* __restrict__ idxb,
                                                    const float* __restrict__ wbs,
                                                    const float* __restrict__ bias,
                                                    const float* __restrict__ v,
                                                    float* __restrict__ out) {
    __shared__ float tile[16][132];
    const int lid = blockIdx.x;                 // 12288 blocks
    const int slot = lid >> 3;                  // 0..1535
    const int b = (lid & 7) + 8 * (slot >> 6);  // 64 tiles/batch
    const int tl = slot & 63;
    const int n0 = (tl & 31) * 16;
    const int f0 = (tl >> 5) * 128;
    const int w = threadIdx.x >> 6;
    const int l = threadIdx.x & 63;

    const float* Xb = X + ((size_t)b << 9) * F_DIM;
    const int rl = l >> 5;                      // row sub-index (0/1)
    const int fq = l & 31;                      // f-quad within half-panel
    float4 bv = ((const float4*)bias)[(f0 >> 2) + fq];

#pragma unroll
    for (int p2 = 0; p2 < 2; ++p2) {
        const int rloc = p2 * 8 + w * 2 + rl;
        const int row = b * N_DIM + n0 + rloc;
        const int* id = idxb + row * K_TOP;
        const float* ww = wbs + (size_t)row * 12;
        float4 xv = ((const float4*)(X + (size_t)row * F_DIM + f0))[fq];
        const float ws = ww[K_TOP];
        float4 acc;
        acc.x = ws * xv.x + bv.x; acc.y = ws * xv.y + bv.y;
        acc.z = ws * xv.z + bv.z; acc.w = ws * xv.w + bv.w;
#pragma unroll
        for (int i = 0; i < K_TOP; ++i) {
            float wi = ww[i];
            float4 gv = ((const float4*)(Xb + ((size_t)id[i] << 8) + f0))[fq];
            acc.x += wi * gv.x; acc.y += wi * gv.y;
            acc.z += wi * gv.z; acc.w += wi * gv.w;
        }
        tile[rloc][fq * 4 + 0] = acc.x;
        tile[rloc][fq * 4 + 1] = acc.y;
        tile[rloc][fq * 4 + 2] = acc.z;
        tile[rloc][fq * 4 + 3] = acc.w;
    }
    __syncthreads();

    const int i4 = l & 3, fj = l >> 2;
#pragma unroll
    for (int k = 0; k < 2; ++k) {
        const int fl = k * 64 + w * 16 + fj;
        const size_t vo = (size_t)b * F_DIM * N_DIM + (size_t)(f0 + fl) * N_DIM + n0;
        float4 vv = ((const float4*)(v + vo))[i4];
        float4 o;
        o.x = tile[i4 * 4 + 0][fl] + vv.x;
        o.y = tile[i4 * 4 + 1][fl] + vv.y;
        o.z = tile[i4 * 4 + 2][fl] + vv.z;
        o.w = tile[i4 * 4 + 3][fl] + vv.w;
        ((float4*)(out + vo))[i4] = o;
    }
}

// ---------------------------------------------------------------------------
extern "C" void kernel_launch(void* const* d_in, const int* in_sizes, int n_in,
                              void* d_out, int out_size, void* d_ws, size_t ws_size,
                              hipStream_t stream) {
    const float* v   = (const float*)d_in[0];
    const float* g_w = (const float*)d_in[1];
    const float* g_b = (const float*)d_in[2];
    const float* w1  = (const float*)d_in[3];
    const float* b1  = (const float*)d_in[4];
    const float* w2  = (const float*)d_in[5];
    const float* b2  = (const float*)d_in[6];
    float* out = (float*)d_out;

    const size_t S = (size_t)B_DIM * N_DIM * F_DIM;
    float* bufA = (float*)d_ws;                     // h1, then h2 (fp32)
    float* bufB = bufA + S;                         // vt/x1bf in lower half
    float* bc   = bufB + S;
    float* deg  = bc + F_DIM;
    float* wb   = deg + (size_t)B_DIM * N_DIM;      // raw top-10 values
    int*   idxb = (int*)(wb + (size_t)B_DIM * N_DIM * (K_TOP + 1));
    unsigned short* Wt1 = (unsigned short*)(idxb + (size_t)B_DIM * N_DIM * K_TOP);
    unsigned short* W2t = Wt1 + F_DIM * F_DIM;

    unsigned short* vt   = (unsigned short*)bufB;   // lower half of bufB
    unsigned short* x1bf = (unsigned short*)bufB;
    float* wbs = bufB + S / 2;                      // upper half of bufB (free)

    k_combine<<<dim3(2 * F_DIM + 2), 256, 0, stream>>>(g_w, g_b, w1, w2, Wt1, bc, W2t);
    k_to_bf16t<<<dim3(N_DIM / 32, F_DIM / 32, B_DIM), 256, 0, stream>>>(v, vt);
    // affinity + top-10 (m-split waves, cached chunk-best selection)
    k_topk_reg<<<dim3(B_DIM * (N_DIM / 32)), 256, 0, stream>>>(vt, deg, idxb, wb);
    // pre-scale edge weights once
    k_scale<<<dim3(B_DIM * N_DIM / 256), 256, 0, stream>>>(deg, idxb, wb, wbs);
    // h1 = vt @ Wt1^T + bc -> bufA  (64x256 blocks, 4 waves/SIMD)
    k_gemm_mfma<true><<<dim3(N_DIM / 64, B_DIM), 256, 0, stream>>>(vt, Wt1, bc, bufA);
    // x1 = relu(A_hat @ h1 + b1) -> x1bf (bf16)
    k_spmm_bf16<<<dim3(B_DIM * N_DIM / 4), 256, 0, stream>>>(bufA, idxb, wbs, b1, x1bf);
    // h2 = x1bf @ W2t^T -> bufA
    k_gemm_mfma<false><<<dim3(N_DIM / 64, B_DIM), 256, 0, stream>>>(x1bf, W2t, nullptr, bufA);
    // out = (A_hat @ h2 + b2)^T + v
    k_spmm_trans<<<dim3(B_DIM * N_DIM / 16 * 2), 256, 0, stream>>>(bufA, idxb, wbs, b2, v, out);
}